// Round 6
// baseline (736.414 us; speedup 1.0000x reference)
//
#include <hip/hip_runtime.h>

#define TB 128  // 2 waves; L1: wave0=fwd, wave1=bwd. L2/L3: wave0 carries both dirs.

typedef float v2f __attribute__((ext_vector_type(2)));

__device__ __forceinline__ float rcp_f(float x) { return __builtin_amdgcn_rcpf(x); }
__device__ __forceinline__ float exp2_f(float x) { return __builtin_amdgcn_exp2f(x); }
// butterfly add with quad_perm DPP (pure VALU, no DS pipe)
__device__ __forceinline__ float dpp_add_xor1(float x) {
  int y = __builtin_amdgcn_update_dpp(0, __float_as_int(x), 0xB1, 0xF, 0xF, true);
  return x + __int_as_float(y);
}
__device__ __forceinline__ float dpp_add_xor2(float x) {
  int y = __builtin_amdgcn_update_dpp(0, __float_as_int(x), 0x4E, 0xF, 0xF, true);
  return x + __int_as_float(y);
}
__device__ __forceinline__ float bperm_f(int addr, float v) {
  return __int_as_float(__builtin_amdgcn_ds_bpermute(addr, __float_as_int(v)));
}

// Lane map (within a direction's wl): lane = 4*j + tau (+16*replica when 4H<lanes).
// Quad j owns cell j; tau splits the K-dim of ALL 4 gate dots of cell j.
// Per step: 2 DPP butterfly stages (VALU) reduce gates; h redistributed with
// Hq ds_bpermutes (loop-invariant addrs). No LDS, no barriers in the loop.
template<int Dq, int H, int T, int INS, int OUTS, bool POOL, bool TOUT>
__device__ __forceinline__ void scan2(const float (*wr)[Dq],   // [4][Dq] input-slice weights (pre-scaled)
                                      const float (*hr)[H / 4],// [4][Hq] recurrent-slice weights
                                      const float* bb,         // [4] bias (nonzero only tau==0)
                                      const float* in_buf, float* out_buf,
                                      int dir, int wl, int laneBase) {
  constexpr int Hq = H / 4;
  const int tau = wl & 3;
  const int j = (wl >> 2) & (H - 1);
  const bool st = (tau == 0) && (wl < 4 * H);  // storing lanes (replica 0, tau 0)
  int baddr[Hq];
#pragma unroll
  for (int m = 0; m < Hq; ++m) baddr[m] = 4 * (laneBase + 4 * (tau * Hq + m));
  float hs[Hq];
#pragma unroll
  for (int m = 0; m < Hq; ++m) hs[m] = 0.f;
  float cs = 0.f, pm = 0.f;
  int t = dir ? (T - 1) : 0;
  const int dt = dir ? -1 : 1;
  const int off = tau * Dq;

  float curA[Dq], curB[Dq];
  auto ldin = [&](float* dst, int tt) {
    tt = tt < 0 ? 0 : (tt > T - 1 ? T - 1 : tt);
    const float* p = in_buf + tt * INS + off;
    *(float4*)dst = *(const float4*)p;
    if constexpr (Dq == 8) *(float4*)(dst + 4) = *(const float4*)(p + 4);
  };
  v2f xa[4];
  auto xwdot = [&](const float* c) {
#pragma unroll
    for (int m = 0; m < 4; ++m) {
      v2f q = {bb[m], 0.f};
#pragma unroll
      for (int i = 0; i < Dq; i += 2)
        q = __builtin_elementwise_fma(*(const v2f*)(wr[m] + i), *(const v2f*)(c + i), q);
      xa[m] = q;
    }
  };
  ldin(curA, t);
  ldin(curB, t + dt);
  xwdot(curA);

  auto body = [&](int s, float* curNext, float* curLoad) {
    float a[4];
#pragma unroll
    for (int m = 0; m < 4; ++m) {
      v2f q = xa[m];
      if constexpr (Hq == 1) {
        q.x = fmaf(hr[m][0], hs[0], q.x);
      } else if constexpr (Hq == 2) {
        q = __builtin_elementwise_fma((v2f){hr[m][0], hr[m][1]}, (v2f){hs[0], hs[1]}, q);
      } else {
        q = __builtin_elementwise_fma((v2f){hr[m][0], hr[m][1]}, (v2f){hs[0], hs[1]}, q);
        q = __builtin_elementwise_fma((v2f){hr[m][2], hr[m][3]}, (v2f){hs[2], hs[3]}, q);
      }
      a[m] = q.x + q.y;
    }
    // all-reduce over the quad (tau groups): 2 VALU DPP stages
#pragma unroll
    for (int m = 0; m < 4; ++m) a[m] = dpp_add_xor1(a[m]);
#pragma unroll
    for (int m = 0; m < 4; ++m) a[m] = dpp_add_xor2(a[m]);
    // weights pre-scaled by log2e (2*log2e for g): sigma via exp2+rcp
    float gi = rcp_f(1.f + exp2_f(-a[0]));
    float gf = rcp_f(1.f + exp2_f(-a[1]));
    float gg = fmaf(2.f, rcp_f(1.f + exp2_f(-a[2])), -1.f);
    float go = rcp_f(1.f + exp2_f(-a[3]));
    cs = fmaf(gf, cs, gi * gg);
    float th = fmaf(2.f, rcp_f(1.f + exp2_f(-2.8853900818f * cs)), -1.f);
    float hv = go * th;  // every lane has h for its cell j
    // redistribute h slices for next step (single DS latency, no barrier)
#pragma unroll
    for (int m = 0; m < Hq; ++m) hs[m] = bperm_f(baddr[m], hv);
    // fill DS-latency window: next step's input dot + depth-2 prefetch
    xwdot(curNext);
    ldin(curLoad, t + 2 * dt);
    if (st) {
      if constexpr (TOUT) {
        out_buf[(dir * H + j) * T + t] = hv;
      } else if constexpr (POOL) {
        if (s & 1) out_buf[(t >> 1) * OUTS + dir * H + j] = fmaxf(pm, hv);
        else pm = hv;
      } else {
        out_buf[t * OUTS + dir * H + j] = hv;
      }
    }
    t += dt;
  };

  for (int s = 0; s < T; s += 2) {  // T even: register ping-pong
    body(s, curB, curA);
    body(s + 1, curA, curB);
  }
}

// Load weights for lane (j,tau): 4 gate rows of cell j, K-slice tau.
// Rows: [2][4H][D]; gate m in {i,f,g,o}; pre-scale by log2e (2x for g).
template<int D, int Dq, int H>
__device__ __forceinline__ void load_wb2(const float* __restrict__ wih,
                                         const float* __restrict__ whh,
                                         const float* __restrict__ bias,
                                         int dir, int wl,
                                         float (*wr)[Dq], float (*hr)[H / 4], float* bb) {
  constexpr int Hq = H / 4;
  constexpr float L2E = 1.4426950408889634f;
  const int tau = wl & 3;
  const int j = (wl >> 2) & (H - 1);
#pragma unroll
  for (int m = 0; m < 4; ++m) {
    const float k = (m == 2) ? 2.f * L2E : L2E;
    const int row = dir * 4 * H + m * H + j;
#pragma unroll
    for (int kk = 0; kk < Dq; ++kk) wr[m][kk] = wih[row * D + tau * Dq + kk] * k;
#pragma unroll
    for (int mm = 0; mm < Hq; ++mm) hr[m][mm] = whh[row * H + tau * Hq + mm] * k;
    bb[m] = (tau == 0) ? bias[row] * k : 0.f;
  }
}

__global__ __launch_bounds__(TB) void lstm_all(
    const float* __restrict__ x,
    const float* __restrict__ conv_w, const float* __restrict__ conv_b,
    const float* __restrict__ bn_g, const float* __restrict__ bn_b,
    const float* __restrict__ bn_m, const float* __restrict__ bn_v,
    const float* __restrict__ w1a_ih, const float* __restrict__ w1a_hh, const float* __restrict__ b1a,
    const float* __restrict__ w1b_ih, const float* __restrict__ w1b_hh, const float* __restrict__ b1b,
    const float* __restrict__ w2a_ih, const float* __restrict__ w2a_hh, const float* __restrict__ b2a,
    const float* __restrict__ w2b_ih, const float* __restrict__ w2b_hh, const float* __restrict__ b2b,
    const float* __restrict__ w3_ih, const float* __restrict__ w3_hh, const float* __restrict__ b3,
    float* __restrict__ out, float* __restrict__ ws, int row0) {
  const int row = row0 + blockIdx.x;
  const int tid = threadIdx.x;
  const int wave = tid >> 6;
  const int lane = tid & 63;

  // LB overlays: phase1 xs[512][16] (8192f, slices of 4 per tau, cols 3/7/11/14/15 pad),
  // then L1b out [256][32] (8192f), then L2b out [128][16] (2048f).
  __shared__ __align__(16) float LB[8192];
  __shared__ __align__(16) float w2c[64][11];
  __shared__ float b2c[64];

  float* A = ws + (size_t)blockIdx.x * 16384;  // 64 KiB per row

  // stage x[row] (11x512): channel c -> slot (c/3)*4 + c%3 (16B-aligned tau-slices)
  float (*xs)[16] = (float(*)[16])LB;
  const float* xrow = x + (size_t)row * 5632;
  for (int i = tid; i < 5632; i += TB) {
    int c = i >> 9, t = i & 511;
    xs[t][(c / 3) * 4 + (c % 3)] = xrow[i];
  }
  // zero the pad slots {3,7,11,14,15} (disjoint from fill, no barrier needed)
  for (int i = tid; i < 512 * 5; i += TB) {
    int t = i / 5, p = i % 5;
    int slot = (p < 3) ? (4 * p + 3) : (p + 11);
    xs[t][slot] = 0.f;
  }
  if (tid < 64) {
    float inv = bn_g[tid] * rsqrtf(bn_v[tid] + 1e-5f);
    for (int c = 0; c < 11; ++c) w2c[tid][c] = conv_w[tid * 11 + c] * inv;
    b2c[tid] = fmaf(conv_b[tid] - bn_m[tid], inv, bn_b[tid]);
  }
  __syncthreads();

  // ---- L1a: conv+BN folded; lane (j,tau) needs Weff[4 gates of j][3 chans of tau]
  {
    constexpr float L2E = 1.4426950408889634f;
    const int tau = lane & 3;
    const int j = (lane >> 2) & 15;
    float weff[4][4], beff[4], hrw[4][4];
#pragma unroll
    for (int m = 0; m < 4; ++m) {
      const float k = (m == 2) ? 2.f * L2E : L2E;
      const int row_l = wave * 64 + m * 16 + j;
      const float* wih = w1a_ih + row_l * 64;
      float acc0 = 0.f, acc1 = 0.f, acc2 = 0.f;
      float bsum = b1a[row_l];
      const int c0 = tau * 3, c1 = tau * 3 + 1, c2 = tau * 3 + 2;
      for (int d = 0; d < 64; ++d) {
        float wd = wih[d];
        bsum = fmaf(wd, b2c[d], bsum);
        acc0 = fmaf(wd, w2c[d][c0], acc0);
        acc1 = fmaf(wd, w2c[d][c1], acc1);
        if (c2 < 11) acc2 = fmaf(wd, w2c[d][c2], acc2);
      }
      weff[m][0] = acc0 * k; weff[m][1] = acc1 * k;
      weff[m][2] = (c2 < 11) ? acc2 * k : 0.f; weff[m][3] = 0.f;
      beff[m] = (tau == 0) ? bsum * k : 0.f;
      const float* q = w1a_hh + row_l * 16 + tau * 4;
#pragma unroll
      for (int mm = 0; mm < 4; ++mm) hrw[m][mm] = q[mm] * k;
    }
    scan2<4, 16, 512, 16, 32, false, false>(weff, hrw, beff, &xs[0][0], A,
                                            wave, lane, 0);
  }
  __syncthreads();

  // ---- L1b + pool: A [512][32] -> LB [256][32]
  {
    float wr[4][8], hr[4][4], bb[4];
    load_wb2<32, 8, 16>(w1b_ih, w1b_hh, b1b, wave, lane, wr, hr, bb);
    scan2<8, 16, 512, 32, 32, true, false>(wr, hr, bb, A, LB, wave, lane, 0);
  }
  __syncthreads();

  // ---- L2a: LB [256][32] -> A [256][16]; merged single wave (dir = lane>>5)
  if (wave == 0) {
    const int dir = lane >> 5, wl = lane & 31;
    float wr[4][8], hr[4][2], bb[4];
    load_wb2<32, 8, 8>(w2a_ih, w2a_hh, b2a, dir, wl, wr, hr, bb);
    scan2<8, 8, 256, 32, 16, false, false>(wr, hr, bb, LB, A, dir, wl, dir * 32);
  }
  __syncthreads();

  // ---- L2b + pool: A [256][16] -> LB [128][16]; merged
  if (wave == 0) {
    const int dir = lane >> 5, wl = lane & 31;
    float wr[4][4], hr[4][2], bb[4];
    load_wb2<16, 4, 8>(w2b_ih, w2b_hh, b2b, dir, wl, wr, hr, bb);
    scan2<4, 8, 256, 16, 16, true, false>(wr, hr, bb, A, LB, dir, wl, dir * 32);
  }
  __syncthreads();

  // ---- L3: LB [128][16] -> out[row][ch][t]; merged
  if (wave == 0) {
    const int dir = lane >> 5, wl = lane & 31;
    float wr[4][4], hr[4][1], bb[4];
    load_wb2<16, 4, 4>(w3_ih, w3_hh, b3, dir, wl, wr, hr, bb);
    scan2<4, 4, 128, 16, 8, false, true>(wr, hr, bb, LB, out + (size_t)row * 1024,
                                         dir, wl, dir * 32);
  }
}

extern "C" void kernel_launch(void* const* d_in, const int* in_sizes, int n_in,
                              void* d_out, int out_size, void* d_ws, size_t ws_size,
                              hipStream_t stream) {
  const float* x      = (const float*)d_in[0];
  const float* conv_w = (const float*)d_in[1];
  const float* conv_b = (const float*)d_in[2];
  const float* bn_g   = (const float*)d_in[3];
  const float* bn_b   = (const float*)d_in[4];
  const float* bn_m   = (const float*)d_in[5];
  const float* bn_v   = (const float*)d_in[6];
  const float* w1a_ih = (const float*)d_in[7];
  const float* w1a_hh = (const float*)d_in[8];
  const float* b1a    = (const float*)d_in[9];
  const float* w1b_ih = (const float*)d_in[10];
  const float* w1b_hh = (const float*)d_in[11];
  const float* b1b    = (const float*)d_in[12];
  const float* w2a_ih = (const float*)d_in[13];
  const float* w2a_hh = (const float*)d_in[14];
  const float* b2a    = (const float*)d_in[15];
  const float* w2b_ih = (const float*)d_in[16];
  const float* w2b_hh = (const float*)d_in[17];
  const float* b2b    = (const float*)d_in[18];
  const float* w3_ih  = (const float*)d_in[19];
  const float* w3_hh  = (const float*)d_in[20];
  const float* b3     = (const float*)d_in[21];

  const size_t per_row_bytes = 16384 * sizeof(float);
  int rows_per = (int)(ws_size / per_row_bytes);
  if (rows_per < 1) rows_per = 1;
  if (rows_per > 1024) rows_per = 1024;

  for (int r0 = 0; r0 < 1024; r0 += rows_per) {
    int n = 1024 - r0;
    if (n > rows_per) n = rows_per;
    lstm_all<<<n, TB, 0, stream>>>(x, conv_w, conv_b, bn_g, bn_b, bn_m, bn_v,
                                   w1a_ih, w1a_hh, b1a, w1b_ih, w1b_hh, b1b,
                                   w2a_ih, w2a_hh, b2a, w2b_ih, w2b_hh, b2b,
                                   w3_ih, w3_hh, b3,
                                   (float*)d_out, (float*)d_ws, r0);
  }
}

// Round 7
// 485.091 us; speedup vs baseline: 1.5181x; 1.5181x over previous
//
#include <hip/hip_runtime.h>

#define TB 128  // 2 waves; L1: wave0=fwd, wave1=bwd. L2/L3: wave0 carries both dirs.

typedef float v2f __attribute__((ext_vector_type(2)));

__device__ __forceinline__ float rcp_f(float x) { return __builtin_amdgcn_rcpf(x); }
__device__ __forceinline__ float exp2_f(float x) { return __builtin_amdgcn_exp2f(x); }
// quad-local DPP exchanges (pure VALU, full rate)
__device__ __forceinline__ float dpp_xor2(float x) {  // lane ^ 2 : quad_perm [2,3,0,1]
  return __int_as_float(__builtin_amdgcn_update_dpp(0, __float_as_int(x), 0x4E, 0xF, 0xF, true));
}
__device__ __forceinline__ float dpp_xor1(float x) {  // lane ^ 1 : quad_perm [1,0,3,2]
  return __int_as_float(__builtin_amdgcn_update_dpp(0, __float_as_int(x), 0xB1, 0xF, 0xF, true));
}

// Lane map (within a direction's wl): lane = 4*j + tau. Quad j owns cell j;
// tau = gate (0:i 1:f 2:g 3:o). Each lane: FULL x-dot + FULL h-dot for its gate
// (r5 register discipline). Gate combine = 3 quad-DPP VALU ops (no LDS).
// One LDS RT per step: tau1 lanes write h[j]; all lanes read h[0..H-1].
template<int D, int H, int T, int INS, int OUTS, bool POOL, bool TOUT>
__device__ __forceinline__ void scan_core(const float* wr, const float* hr,
                                          float bb, float am, float ab,
                                          const float* in_buf, float* out_buf,
                                          int dir, int wl, float* h_base) {
  const int tau = wl & 3;
  const int j = (wl >> 2) & (H - 1);
  const bool st = (tau == 1) && ((wl >> 2) < H);  // h-writer + out-store lanes
  if (wl < H) h_base[wl] = 0.f;
  __builtin_amdgcn_wave_barrier();

  int t = dir ? (T - 1) : 0;
  const int dt = dir ? -1 : 1;

  float curA[D], curB[D];
  auto ldin = [&](float* dst, int tt) {
    tt = tt < 0 ? 0 : (tt > T - 1 ? T - 1 : tt);
    const float* p = in_buf + tt * INS;
#pragma unroll
    for (int i = 0; i < D; i += 4) *(float4*)(dst + i) = *(const float4*)(p + i);
  };
  auto xwdot = [&](const float* c) -> float {
    v2f q0 = {bb, 0.f}, q1 = {0.f, 0.f};
#pragma unroll
    for (int i = 0; i < D; i += 4) {
      q0 = __builtin_elementwise_fma(*(const v2f*)(wr + i), *(const v2f*)(c + i), q0);
      q1 = __builtin_elementwise_fma(*(const v2f*)(wr + i + 2), *(const v2f*)(c + i + 2), q1);
    }
    v2f qs = q0 + q1;
    return qs.x + qs.y;
  };

  ldin(curA, t);
  ldin(curB, t + dt);
  float xw = xwdot(curA);
  float cs = 0.f, pm = 0.f;

  auto body = [&](int s, float* curNext, float* curLoad) {
    // h broadcast read (single RT; h written by tau1 lanes last step)
    v2f r0 = {xw, 0.f}, r1 = {0.f, 0.f};
#pragma unroll
    for (int i = 0; i < H; i += 4) {
      float4 h4 = *(const float4*)(h_base + i);
      r0 = __builtin_elementwise_fma(*(const v2f*)(hr + i), (v2f){h4.x, h4.y}, r0);
      r1 = __builtin_elementwise_fma(*(const v2f*)(hr + i + 2), (v2f){h4.z, h4.w}, r1);
    }
    v2f rs = r0 + r1;
    float acc = rs.x + rs.y;
    // weights pre-scaled by log2e (2x for g): i,f,o -> sigmoid; g -> tanh
    float e2 = exp2_f(-acc);
    float sg = rcp_f(1.f + e2);
    float a = fmaf(am, sg, ab);
    // quad gate combine: b = partner(^2): i<->g, f<->o ; q = (i*g) delivered ^1
    float b = dpp_xor2(a);
    float p = a * b;
    float q = dpp_xor1(p);
    // tau1: f=a,o=b ; tau3: o=a,f=b (tau0/2 compute junk, never stored)
    float fv = (tau == 1) ? a : b;
    float ov = (tau == 1) ? b : a;
    cs = fmaf(fv, cs, q);                              // c = f*c + i*g
    float th = fmaf(2.f, rcp_f(1.f + exp2_f(-2.8853900818f * cs)), -1.f);
    float hv = ov * th;                                // h = o * tanh(c)
    if (st) h_base[j] = hv;                            // 16 distinct banks
    __builtin_amdgcn_wave_barrier();
    // fill latency window: next step's input dot + depth-2 prefetch
    xw = xwdot(curNext);
    ldin(curLoad, t + 2 * dt);
    if (st) {
      if constexpr (TOUT) {
        out_buf[(dir * H + j) * T + t] = hv;
      } else if constexpr (POOL) {
        if (s & 1) out_buf[(t >> 1) * OUTS + dir * H + j] = fmaxf(pm, hv);
        else pm = hv;
      } else {
        out_buf[t * OUTS + dir * H + j] = hv;
      }
    }
    t += dt;
  };

  for (int s = 0; s < T; s += 2) {  // T even: register ping-pong
    body(s, curB, curA);
    body(s + 1, curA, curB);
  }
}

// Weight rows: [2][4H][.]; lane (j,tau) loads row dir*4H + tau*H + j,
// pre-scaled by log2e (2*log2e for the g gate).
template<int D, int H>
__device__ __forceinline__ void load_wb(const float* __restrict__ wih,
                                        const float* __restrict__ whh,
                                        const float* __restrict__ bias,
                                        int dir, int wl,
                                        float* wr, float* hr, float& bb,
                                        float& am, float& ab) {
  constexpr float L2E = 1.4426950408889634f;
  const int tau = wl & 3;
  const int j = (wl >> 2) & (H - 1);
  const bool isg = (tau == 2);
  const float k = isg ? 2.f * L2E : L2E;
  am = isg ? 2.f : 1.f;
  ab = isg ? -1.f : 0.f;
  const int row = dir * 4 * H + tau * H + j;
  const float* p = wih + row * D;
#pragma unroll
  for (int i = 0; i < D; i += 4) {
    float4 v = *(const float4*)(p + i);
    wr[i] = v.x * k; wr[i + 1] = v.y * k; wr[i + 2] = v.z * k; wr[i + 3] = v.w * k;
  }
  const float* q = whh + row * H;
#pragma unroll
  for (int i = 0; i < H; ++i) hr[i] = q[i] * k;
  bb = bias[row] * k;
}

__global__ __launch_bounds__(TB) void lstm_all(
    const float* __restrict__ x,
    const float* __restrict__ conv_w, const float* __restrict__ conv_b,
    const float* __restrict__ bn_g, const float* __restrict__ bn_b,
    const float* __restrict__ bn_m, const float* __restrict__ bn_v,
    const float* __restrict__ w1a_ih, const float* __restrict__ w1a_hh, const float* __restrict__ b1a,
    const float* __restrict__ w1b_ih, const float* __restrict__ w1b_hh, const float* __restrict__ b1b,
    const float* __restrict__ w2a_ih, const float* __restrict__ w2a_hh, const float* __restrict__ b2a,
    const float* __restrict__ w2b_ih, const float* __restrict__ w2b_hh, const float* __restrict__ b2b,
    const float* __restrict__ w3_ih, const float* __restrict__ w3_hh, const float* __restrict__ b3,
    float* __restrict__ out, float* __restrict__ ws, int row0) {
  const int row = row0 + blockIdx.x;
  const int tid = threadIdx.x;
  const int wave = tid >> 6;
  const int lane = tid & 63;

  // LB overlays: phase1 xs[512][12] (6144f), then L1b out [256][32] (8192f),
  // then L2b out [128][16] (2048f).
  __shared__ __align__(16) float LB[8192];
  __shared__ __align__(16) float w2c[64][11];
  __shared__ float b2c[64];
  __shared__ __align__(16) float hb[32];  // h state, 16 per direction

  float* A = ws + (size_t)blockIdx.x * 16384;  // 64 KiB per row

  // stage x[row] (11x512) transposed into LDS; zero pad col
  float (*xs)[12] = (float(*)[12])LB;
  const float* xrow = x + (size_t)row * 5632;
  for (int i = tid; i < 5632; i += TB) {
    int c = i >> 9, t = i & 511;
    xs[t][c] = xrow[i];
  }
  for (int i = tid; i < 512; i += TB) xs[i][11] = 0.f;
  if (tid < 64) {
    float inv = bn_g[tid] * rsqrtf(bn_v[tid] + 1e-5f);
    for (int c = 0; c < 11; ++c) w2c[tid][c] = conv_w[tid * 11 + c] * inv;
    b2c[tid] = fmaf(conv_b[tid] - bn_m[tid], inv, bn_b[tid]);
  }
  __syncthreads();

  // ---- L1a: conv+BN folded into 12-wide effective weights; dir = wave
  {
    constexpr float L2E = 1.4426950408889634f;
    const int tau = lane & 3;
    const int j = lane >> 2;  // 0..15
    const int row_l = wave * 64 + tau * 16 + j;
    float weff[12], beff;
#pragma unroll
    for (int c = 0; c < 12; ++c) weff[c] = 0.f;
    const float* wih = w1a_ih + row_l * 64;
    beff = b1a[row_l];
    for (int d = 0; d < 64; ++d) {
      float wd = wih[d];
      beff = fmaf(wd, b2c[d], beff);
#pragma unroll
      for (int c = 0; c < 11; ++c) weff[c] = fmaf(wd, w2c[d][c], weff[c]);
    }
    const bool isg = (tau == 2);
    const float k = isg ? 2.f * L2E : L2E;
#pragma unroll
    for (int c = 0; c < 12; ++c) weff[c] *= k;
    beff *= k;
    float am = isg ? 2.f : 1.f, ab = isg ? -1.f : 0.f;
    float hrw[16];
    const float* q = w1a_hh + row_l * 16;
#pragma unroll
    for (int i = 0; i < 16; ++i) hrw[i] = q[i] * k;
    scan_core<12, 16, 512, 12, 32, false, false>(weff, hrw, beff, am, ab,
        &xs[0][0], A, wave, lane, hb + wave * 16);
  }
  __syncthreads();

  // ---- L1b + pool: A [512][32] -> LB [256][32]; dir = wave
  {
    float wr[32], hr[16], bb, am, ab;
    load_wb<32, 16>(w1b_ih, w1b_hh, b1b, wave, lane, wr, hr, bb, am, ab);
    scan_core<32, 16, 512, 32, 32, true, false>(wr, hr, bb, am, ab,
        A, LB, wave, lane, hb + wave * 16);
  }
  __syncthreads();

  // ---- L2a: LB [256][32] -> A [256][16]; merged single wave (dir = lane>>5)
  if (wave == 0) {
    const int dir = lane >> 5, wl = lane & 31;
    float wr[32], hr[8], bb, am, ab;
    load_wb<32, 8>(w2a_ih, w2a_hh, b2a, dir, wl, wr, hr, bb, am, ab);
    scan_core<32, 8, 256, 32, 16, false, false>(wr, hr, bb, am, ab,
        LB, A, dir, wl, hb + dir * 16);
  }
  __syncthreads();

  // ---- L2b + pool: A [256][16] -> LB [128][16]; merged
  if (wave == 0) {
    const int dir = lane >> 5, wl = lane & 31;
    float wr[16], hr[8], bb, am, ab;
    load_wb<16, 8>(w2b_ih, w2b_hh, b2b, dir, wl, wr, hr, bb, am, ab);
    scan_core<16, 8, 256, 16, 16, true, false>(wr, hr, bb, am, ab,
        A, LB, dir, wl, hb + dir * 16);
  }
  __syncthreads();

  // ---- L3: LB [128][16] -> out[row][ch][t]; merged
  if (wave == 0) {
    const int dir = lane >> 5, wl = lane & 31;
    float wr[16], hr[4], bb, am, ab;
    load_wb<16, 4>(w3_ih, w3_hh, b3, dir, wl, wr, hr, bb, am, ab);
    scan_core<16, 4, 128, 16, 8, false, true>(wr, hr, bb, am, ab,
        LB, out + (size_t)row * 1024, dir, wl, hb + dir * 16);
  }
}

extern "C" void kernel_launch(void* const* d_in, const int* in_sizes, int n_in,
                              void* d_out, int out_size, void* d_ws, size_t ws_size,
                              hipStream_t stream) {
  const float* x      = (const float*)d_in[0];
  const float* conv_w = (const float*)d_in[1];
  const float* conv_b = (const float*)d_in[2];
  const float* bn_g   = (const float*)d_in[3];
  const float* bn_b   = (const float*)d_in[4];
  const float* bn_m   = (const float*)d_in[5];
  const float* bn_v   = (const float*)d_in[6];
  const float* w1a_ih = (const float*)d_in[7];
  const float* w1a_hh = (const float*)d_in[8];
  const float* b1a    = (const float*)d_in[9];
  const float* w1b_ih = (const float*)d_in[10];
  const float* w1b_hh = (const float*)d_in[11];
  const float* b1b    = (const float*)d_in[12];
  const float* w2a_ih = (const float*)d_in[13];
  const float* w2a_hh = (const float*)d_in[14];
  const float* b2a    = (const float*)d_in[15];
  const float* w2b_ih = (const float*)d_in[16];
  const float* w2b_hh = (const float*)d_in[17];
  const float* b2b    = (const float*)d_in[18];
  const float* w3_ih  = (const float*)d_in[19];
  const float* w3_hh  = (const float*)d_in[20];
  const float* b3     = (const float*)d_in[21];

  const size_t per_row_bytes = 16384 * sizeof(float);
  int rows_per = (int)(ws_size / per_row_bytes);
  if (rows_per < 1) rows_per = 1;
  if (rows_per > 1024) rows_per = 1024;

  for (int r0 = 0; r0 < 1024; r0 += rows_per) {
    int n = 1024 - r0;
    if (n > rows_per) n = rows_per;
    lstm_all<<<n, TB, 0, stream>>>(x, conv_w, conv_b, bn_g, bn_b, bn_m, bn_v,
                                   w1a_ih, w1a_hh, b1a, w1b_ih, w1b_hh, b1b,
                                   w2a_ih, w2a_hh, b2a, w2b_ih, w2b_hh, b2b,
                                   w3_ih, w3_hh, b3,
                                   (float*)d_out, (float*)d_ws, r0);
  }
}

// Round 8
// 393.503 us; speedup vs baseline: 1.8714x; 1.2327x over previous
//
#include <hip/hip_runtime.h>

#define TB 128  // 2 waves; L1: wave0=fwd, wave1=bwd. L2/L3: wave0 carries both dirs.

typedef float v2f __attribute__((ext_vector_type(2)));
typedef _Float16 f16;
typedef _Float16 h2v __attribute__((ext_vector_type(2)));

__device__ __forceinline__ float rcp_f(float x) { return __builtin_amdgcn_rcpf(x); }
__device__ __forceinline__ float exp2_f(float x) { return __builtin_amdgcn_exp2f(x); }
__device__ __forceinline__ float dpp_xor2(float x) {  // lane^2: quad_perm [2,3,0,1]
  return __int_as_float(__builtin_amdgcn_update_dpp(0, __float_as_int(x), 0x4E, 0xF, 0xF, true));
}
__device__ __forceinline__ float dpp_xor1(float x) {  // lane^1: quad_perm [1,0,3,2]
  return __int_as_float(__builtin_amdgcn_update_dpp(0, __float_as_int(x), 0xB1, 0xF, 0xF, true));
}

#if __has_builtin(__builtin_amdgcn_fdot2)
__device__ __forceinline__ float fdot2(h2v a, h2v b, float c) {
  return __builtin_amdgcn_fdot2(a, b, c, false);
}
#else
__device__ __forceinline__ float fdot2(h2v a, h2v b, float c) {
  return fmaf((float)a.x, (float)b.x, fmaf((float)a.y, (float)b.y, c));
}
#endif

// Lane map (within direction's wl): lane = 4*j + tau. Quad j owns cell j; tau =
// gate (0:i 1:f 2:g 3:o). Full x-dot + full h-dot per lane; gate combine = 3
// quad-DPP VALU ops. One LDS RT per step (h). DEPTH-deep register prefetch of
// the input row covers memory latency (4 for global f16 input, 2 for LDS).
template<int D, int H, int T, int INS, int OUTS, int DEPTH, bool HIN,
         bool POOL, bool TOUT, typename OutT, typename InT>
__device__ __forceinline__ void scan(const void* wv, const float* hr,
                                     float bb, float am, float ab,
                                     const InT* in, OutT* out,
                                     int dir, int wl, float* h_base) {
  constexpr int NF4 = HIN ? (D / 8) : (D / 4);
  const int tau = wl & 3;
  const int j = (wl >> 2) & (H - 1);
  const bool st = (tau == 1) && ((wl >> 2) < H);
  if (wl < H) h_base[wl] = 0.f;
  __builtin_amdgcn_wave_barrier();

  int t = dir ? (T - 1) : 0;
  const int dt = dir ? -1 : 1;

  float4 bufs[DEPTH][NF4];
  auto ldin = [&](float4* dst, int tt) {
    tt = tt < 0 ? 0 : (tt > T - 1 ? T - 1 : tt);
    const float4* p = (const float4*)((const char*)in + (size_t)tt * INS * sizeof(InT));
#pragma unroll
    for (int i = 0; i < NF4; ++i) dst[i] = p[i];
  };
  auto xwdot = [&](const float4* b) -> float {
    if constexpr (HIN) {
      const h2v* hp = (const h2v*)b;
      const h2v* wh = (const h2v*)wv;
      float a0 = bb, a1 = 0.f, a2 = 0.f, a3 = 0.f;
#pragma unroll
      for (int i = 0; i < D / 2; i += 4) {
        a0 = fdot2(wh[i + 0], hp[i + 0], a0);
        a1 = fdot2(wh[i + 1], hp[i + 1], a1);
        a2 = fdot2(wh[i + 2], hp[i + 2], a2);
        a3 = fdot2(wh[i + 3], hp[i + 3], a3);
      }
      return (a0 + a1) + (a2 + a3);
    } else {
      const float* c = (const float*)b;
      const float* wr = (const float*)wv;
      v2f q0 = {bb, 0.f}, q1 = {0.f, 0.f};
#pragma unroll
      for (int i = 0; i < D; i += 4) {
        q0 = __builtin_elementwise_fma(*(const v2f*)(wr + i), *(const v2f*)(c + i), q0);
        q1 = __builtin_elementwise_fma(*(const v2f*)(wr + i + 2), *(const v2f*)(c + i + 2), q1);
      }
      v2f qs = q0 + q1;
      return qs.x + qs.y;
    }
  };

#pragma unroll
  for (int k = 0; k < DEPTH; ++k) ldin(bufs[k], t + k * dt);
  float xw = xwdot(bufs[0]);
  float cs = 0.f, pm = 0.f;

  for (int s = 0; s < T; s += DEPTH) {
#pragma unroll
    for (int k = 0; k < DEPTH; ++k) {
      // h broadcast read (single RT; h written by tau1 lanes last step)
      v2f r0 = {xw, 0.f}, r1 = {0.f, 0.f};
#pragma unroll
      for (int i = 0; i < H; i += 4) {
        float4 h4 = *(const float4*)(h_base + i);
        r0 = __builtin_elementwise_fma(*(const v2f*)(hr + i), (v2f){h4.x, h4.y}, r0);
        r1 = __builtin_elementwise_fma(*(const v2f*)(hr + i + 2), (v2f){h4.z, h4.w}, r1);
      }
      v2f rs = r0 + r1;
      float acc = rs.x + rs.y;
      // weights pre-scaled by log2e (2x for g): i,f,o -> sigmoid; g -> tanh
      float sg = rcp_f(1.f + exp2_f(-acc));
      float a = fmaf(am, sg, ab);
      // quad combine: b = partner(^2): i<->g, f<->o ; q = (i*g) delivered ^1
      float b = dpp_xor2(a);
      float p = a * b;
      float q = dpp_xor1(p);
      float fv = (tau == 1) ? a : b;
      float ov = (tau == 1) ? b : a;
      cs = fmaf(fv, cs, q);                              // c = f*c + i*g
      float th = fmaf(2.f, rcp_f(1.f + exp2_f(-2.8853900818f * cs)), -1.f);
      float hv = ov * th;                                // h = o * tanh(c)
      if (st) h_base[j] = hv;
      __builtin_amdgcn_wave_barrier();
      // fill latency window: next step's x-dot, then reload this buffer t+DEPTH
      xw = xwdot(bufs[(k + 1) % DEPTH]);
      ldin(bufs[k], t + DEPTH * dt);
      if (st) {
        if constexpr (TOUT) {
          out[(dir * H + j) * T + t] = (OutT)hv;
        } else if constexpr (POOL) {
          if ((s + k) & 1) out[(t >> 1) * OUTS + dir * H + j] = (OutT)fmaxf(pm, hv);
          else pm = hv;
        } else {
          out[t * OUTS + dir * H + j] = (OutT)hv;
        }
      }
      t += dt;
    }
  }
}

// f32 weights (rows [2][4H][.]) -> per-lane h2 input weights + f32 recurrent
// weights, pre-scaled by log2e (2*log2e for g gate).
template<int D, int H>
__device__ __forceinline__ void load_wbh(const float* __restrict__ wih,
                                         const float* __restrict__ whh,
                                         const float* __restrict__ bias,
                                         int dir, int wl,
                                         h2v* wh, float* hr, float& bb,
                                         float& am, float& ab) {
  constexpr float L2E = 1.4426950408889634f;
  const int tau = wl & 3;
  const int j = (wl >> 2) & (H - 1);
  const bool isg = (tau == 2);
  const float k = isg ? 2.f * L2E : L2E;
  am = isg ? 2.f : 1.f;
  ab = isg ? -1.f : 0.f;
  const int row = dir * 4 * H + tau * H + j;
  const float* p = wih + row * D;
#pragma unroll
  for (int i = 0; i < D / 2; ++i)
    wh[i] = (h2v){(f16)(p[2 * i] * k), (f16)(p[2 * i + 1] * k)};
  const float* q = whh + row * H;
#pragma unroll
  for (int i = 0; i < H; ++i) hr[i] = q[i] * k;
  bb = bias[row] * k;
}

__global__ __launch_bounds__(TB) void lstm_all(
    const float* __restrict__ x,
    const float* __restrict__ conv_w, const float* __restrict__ conv_b,
    const float* __restrict__ bn_g, const float* __restrict__ bn_b,
    const float* __restrict__ bn_m, const float* __restrict__ bn_v,
    const float* __restrict__ w1a_ih, const float* __restrict__ w1a_hh, const float* __restrict__ b1a,
    const float* __restrict__ w1b_ih, const float* __restrict__ w1b_hh, const float* __restrict__ b1b,
    const float* __restrict__ w2a_ih, const float* __restrict__ w2a_hh, const float* __restrict__ b2a,
    const float* __restrict__ w2b_ih, const float* __restrict__ w2b_hh, const float* __restrict__ b2b,
    const float* __restrict__ w3_ih, const float* __restrict__ w3_hh, const float* __restrict__ b3,
    float* __restrict__ out, f16* __restrict__ ws, int row0) {
  const int row = row0 + blockIdx.x;
  const int tid = threadIdx.x;
  const int wave = tid >> 6;
  const int lane = tid & 63;

  // R1 (24 KB): phase1 xs f32[512][12]; later LBh f16[256][32] (16K) at +0
  // and LB2h f16[128][16] (4K) at +16384.
  __shared__ __align__(16) char R1[24576];
  __shared__ __align__(16) f16 A2h[256 * 16];  // 8 KB (L2a out / L2b in)
  __shared__ __align__(16) float w2c[64][11];
  __shared__ float b2c[64];
  __shared__ __align__(16) float hb[32];  // h state, 16 per direction

  float (*xs)[12] = (float(*)[12])R1;
  f16* LBh = (f16*)R1;
  f16* LB2h = (f16*)(R1 + 16384);
  f16* Ah = ws + (size_t)blockIdx.x * 16384;  // 32 KB per row (512*32 halves)

  // stage x[row] (11x512) transposed into LDS; zero pad col
  const float* xrow = x + (size_t)row * 5632;
  for (int i = tid; i < 5632; i += TB) {
    int c = i >> 9, t = i & 511;
    xs[t][c] = xrow[i];
  }
  for (int i = tid; i < 512; i += TB) xs[i][11] = 0.f;
  if (tid < 64) {
    float inv = bn_g[tid] * rsqrtf(bn_v[tid] + 1e-5f);
    for (int c = 0; c < 11; ++c) w2c[tid][c] = conv_w[tid * 11 + c] * inv;
    b2c[tid] = fmaf(conv_b[tid] - bn_m[tid], inv, bn_b[tid]);
  }
  __syncthreads();

  // ---- L1a: conv+BN folded into 12-wide effective f32 weights; dir = wave
  {
    constexpr float L2E = 1.4426950408889634f;
    const int tau = lane & 3;
    const int j = lane >> 2;  // 0..15
    const int row_l = wave * 64 + tau * 16 + j;
    float weff[12], beff;
#pragma unroll
    for (int c = 0; c < 12; ++c) weff[c] = 0.f;
    const float* wih = w1a_ih + row_l * 64;
    beff = b1a[row_l];
    for (int d = 0; d < 64; ++d) {
      float wd = wih[d];
      beff = fmaf(wd, b2c[d], beff);
#pragma unroll
      for (int c = 0; c < 11; ++c) weff[c] = fmaf(wd, w2c[d][c], weff[c]);
    }
    const bool isg = (tau == 2);
    const float k = isg ? 2.f * L2E : L2E;
#pragma unroll
    for (int c = 0; c < 12; ++c) weff[c] *= k;
    beff *= k;
    float am = isg ? 2.f : 1.f, ab = isg ? -1.f : 0.f;
    float hrw[16];
    const float* q = w1a_hh + row_l * 16;
#pragma unroll
    for (int i = 0; i < 16; ++i) hrw[i] = q[i] * k;
    // xs (LDS f32) -> Ah (global f16), depth-2
    scan<12, 16, 512, 12, 32, 2, false, false, false, f16, float>(
        weff, hrw, beff, am, ab, &xs[0][0], Ah, wave, lane, hb + wave * 16);
  }
  __syncthreads();

  // ---- L1b + pool: Ah (global f16, depth-4 prefetch) -> LBh (LDS f16)
  {
    h2v wh[16]; float hr[16], bb, am, ab;
    load_wbh<32, 16>(w1b_ih, w1b_hh, b1b, wave, lane, wh, hr, bb, am, ab);
    scan<32, 16, 512, 32, 32, 4, true, true, false, f16, f16>(
        wh, hr, bb, am, ab, Ah, LBh, wave, lane, hb + wave * 16);
  }
  __syncthreads();

  // ---- L2a: LBh -> A2h; merged single wave (dir = lane>>5)
  if (wave == 0) {
    const int dir = lane >> 5, wl = lane & 31;
    h2v wh[16]; float hr[8], bb, am, ab;
    load_wbh<32, 8>(w2a_ih, w2a_hh, b2a, dir, wl, wh, hr, bb, am, ab);
    scan<32, 8, 256, 32, 16, 2, true, false, false, f16, f16>(
        wh, hr, bb, am, ab, LBh, A2h, dir, wl, hb + dir * 16);
  }
  __syncthreads();

  // ---- L2b + pool: A2h -> LB2h; merged
  if (wave == 0) {
    const int dir = lane >> 5, wl = lane & 31;
    h2v wh[8]; float hr[8], bb, am, ab;
    load_wbh<16, 8>(w2b_ih, w2b_hh, b2b, dir, wl, wh, hr, bb, am, ab);
    scan<16, 8, 256, 16, 16, 2, true, true, false, f16, f16>(
        wh, hr, bb, am, ab, A2h, LB2h, dir, wl, hb + dir * 16);
  }
  __syncthreads();

  // ---- L3: LB2h -> out[row][ch][t] (f32, transposed store); merged
  if (wave == 0) {
    const int dir = lane >> 5, wl = lane & 31;
    h2v wh[8]; float hr[4], bb, am, ab;
    load_wbh<16, 4>(w3_ih, w3_hh, b3, dir, wl, wh, hr, bb, am, ab);
    scan<16, 4, 128, 16, 8, 2, true, false, true, float, f16>(
        wh, hr, bb, am, ab, LB2h, out + (size_t)row * 1024, dir, wl, hb + dir * 16);
  }
}

extern "C" void kernel_launch(void* const* d_in, const int* in_sizes, int n_in,
                              void* d_out, int out_size, void* d_ws, size_t ws_size,
                              hipStream_t stream) {
  const float* x      = (const float*)d_in[0];
  const float* conv_w = (const float*)d_in[1];
  const float* conv_b = (const float*)d_in[2];
  const float* bn_g   = (const float*)d_in[3];
  const float* bn_b   = (const float*)d_in[4];
  const float* bn_m   = (const float*)d_in[5];
  const float* bn_v   = (const float*)d_in[6];
  const float* w1a_ih = (const float*)d_in[7];
  const float* w1a_hh = (const float*)d_in[8];
  const float* b1a    = (const float*)d_in[9];
  const float* w1b_ih = (const float*)d_in[10];
  const float* w1b_hh = (const float*)d_in[11];
  const float* b1b    = (const float*)d_in[12];
  const float* w2a_ih = (const float*)d_in[13];
  const float* w2a_hh = (const float*)d_in[14];
  const float* b2a    = (const float*)d_in[15];
  const float* w2b_ih = (const float*)d_in[16];
  const float* w2b_hh = (const float*)d_in[17];
  const float* b2b    = (const float*)d_in[18];
  const float* w3_ih  = (const float*)d_in[19];
  const float* w3_hh  = (const float*)d_in[20];
  const float* b3     = (const float*)d_in[21];

  const size_t per_row_bytes = 16384 * sizeof(f16);  // 32 KiB
  int rows_per = (int)(ws_size / per_row_bytes);
  if (rows_per < 1) rows_per = 1;
  if (rows_per > 1024) rows_per = 1024;

  for (int r0 = 0; r0 < 1024; r0 += rows_per) {
    int n = 1024 - r0;
    if (n > rows_per) n = rows_per;
    lstm_all<<<n, TB, 0, stream>>>(x, conv_w, conv_b, bn_g, bn_b, bn_m, bn_v,
                                   w1a_ih, w1a_hh, b1a, w1b_ih, w1b_hh, b1b,
                                   w2a_ih, w2a_hh, b2a, w2b_ih, w2b_hh, b2b,
                                   w3_ih, w3_hh, b3,
                                   (float*)d_out, (f16*)d_ws, r0);
  }
}